// Round 16
// baseline (590.432 us; speedup 1.0000x reference)
//
#include <hip/hip_runtime.h>

#define DD 1024
#define LL 128
#define NSEG 64
#define CHS 544        // fp8 tile chunk stride (512 + 32 pad)
#define TB  17408      // one fp8 tile buffer (32 * CHS)
#define GRID 768       // persistent blocks (3/CU x 256)
#define NTILE 16384    // N / 16
#define SGRID 256      // segment kernel: persistent, all-resident

typedef float floatx4 __attribute__((ext_vector_type(4)));
typedef float f4v __attribute__((ext_vector_type(4)));

// ---- prep: fragment-order fp8 W (x16), zero score_raw + denom + counter ----
// Wf8 gid = c*8192 + ct*512 + lane*8 + j  holds  W[ct*16+(lane&15)][c*32+(lane>>4)*8+j] * 16
__global__ __launch_bounds__(256)
void prep_kernel(const float* __restrict__ Wa, const float* __restrict__ Wb,
                 unsigned char* __restrict__ Wf8, float* __restrict__ denom,
                 unsigned* __restrict__ counter, float* __restrict__ score_raw)
{
    int gid = blockIdx.x * 256 + threadIdx.x;
    if (gid < 2 * LL * DD) {
        const int j    = gid & 7;
        const int lane = (gid >> 3) & 63;
        const int ct   = (gid >> 9) & 15;
        const int c    = gid >> 13;
        const int r = ct * 16 + (lane & 15);
        const int k = c * 32 + (lane >> 4) * 8 + j;
        const float v = ((r < LL) ? Wa[r * DD + k] : Wb[(r - LL) * DD + k]) * 16.0f;
        unsigned u = __builtin_amdgcn_cvt_pk_fp8_f32(v, v, 0, false);
        Wf8[gid] = (unsigned char)(u & 0xFF);
        score_raw[gid] = 0.0f;          // gid range == N exactly
    }
    if (gid < NSEG) denom[gid] = 0.0f;
    if (gid == NSEG) *counter = 0u;
}

// ---- fused, persistent: dbuf fp8 tile, 1 barrier/tile, NT feat loads ----
__global__ __launch_bounds__(512, 6)
void fused_main(const float* __restrict__ feat,
                const unsigned char* __restrict__ Wf8,
                const float* __restrict__ ba,
                const float* __restrict__ bb,
                const float* __restrict__ Wc,
                float* __restrict__ out_norm,
                float* __restrict__ score_raw)
{
    __shared__ __align__(16) char tile[2 * TB];     // 34816 B

    const int tid  = threadIdx.x;
    const int wave = tid >> 6;          // 0..7
    const int lane = tid & 63;
    const int s15  = lane & 15;
    const int l4   = lane >> 4;

    const float bav = ba[wave * 16 + s15];
    const float bbv = bb[wave * 16 + s15];
    const float wcv = Wc[wave * 16 + s15];
    const unsigned char* bb0 = Wf8 + (size_t)wave * 512 + (size_t)lane * 8;

    f4v L[2][4];                        // prefetched rows (wave*2, wave*2+1)

    auto issue = [&](long long T) {
        const float* fb = feat + ((size_t)T * 16 + wave * 2) * DD + lane * 4;
        #pragma unroll
        for (int i = 0; i < 2; ++i)
            #pragma unroll
            for (int c = 0; c < 4; ++c)
                L[i][c] = __builtin_nontemporal_load(
                    reinterpret_cast<const f4v*>(fb + (size_t)i * DD + c * 256));
    };

    long long t = blockIdx.x;
    int parity = 0;
    if (t < NTILE) issue(t);

    while (t < NTILE) {
        const long long row0 = t * 16;
        char* tb = tile + parity * TB;

        // ---- consume L(t) on arrival: norm + out_norm store + fp8 pack ----
        unsigned pw[2][4];
        #pragma unroll
        for (int i = 0; i < 2; ++i) {
            float ss = 0.0f;
            #pragma unroll
            for (int c = 0; c < 4; ++c)
                ss += L[i][c][0]*L[i][c][0] + L[i][c][1]*L[i][c][1]
                    + L[i][c][2]*L[i][c][2] + L[i][c][3]*L[i][c][3];
            #pragma unroll
            for (int off = 32; off >= 1; off >>= 1) ss += __shfl_xor(ss, off);
            const float rinv = 1.0f / fmaxf(sqrtf(ss), 1e-12f);

            float* ob = out_norm + (row0 + wave * 2 + i) * DD + lane * 4;
            #pragma unroll
            for (int c = 0; c < 4; ++c) {
                f4v v;
                v[0] = L[i][c][0] * rinv; v[1] = L[i][c][1] * rinv;
                v[2] = L[i][c][2] * rinv; v[3] = L[i][c][3] * rinv;
                *reinterpret_cast<f4v*>(ob + c * 256) = v;
            }
            #pragma unroll
            for (int c = 0; c < 4; ++c) {
                unsigned u = __builtin_amdgcn_cvt_pk_fp8_f32(L[i][c][0] * 8.0f, L[i][c][1] * 8.0f, 0, false);
                u = __builtin_amdgcn_cvt_pk_fp8_f32(L[i][c][2] * 8.0f, L[i][c][3] * 8.0f, u, true);
                pw[i][c] = u;
            }
        }

        // ---- refill L for next tile IMMEDIATELY (L is dead after pw) ----
        const long long tn = t + GRID;
        if (tn < NTILE) issue(tn);

        // ---- ds_write into buf[parity]; readers of this buf were 2 barriers ago ----
        #pragma unroll
        for (int i = 0; i < 2; ++i) {
            const int r = wave * 2 + i;
            #pragma unroll
            for (int c = 0; c < 4; ++c) {
                const int chunk = (lane >> 3) + c * 8;
                const int addr  = parity * TB + chunk * CHS + r * 32 + ((lane >> 1) & 3) * 8 + (lane & 1) * 4;
                *reinterpret_cast<unsigned*>(tile + addr) = pw[i][c];
            }
        }
        __builtin_amdgcn_sched_barrier(0);

        __syncthreads();                 // single barrier: buf[parity] fully written

        // ---- Phase B: fp8 MFMA; wave owns output cols [wave*16, +16) ----
        floatx4 acc0 = (floatx4)0.0f;
        floatx4 acc1 = (floatx4)0.0f;
        #pragma unroll 4
        for (int c = 0; c < 32; ++c) {
            const long long a8 = *reinterpret_cast<const long long*>(tb + c * CHS + s15 * 32 + l4 * 8);
            const long long w0 = *reinterpret_cast<const long long*>(bb0 + (size_t)c * 8192);
            const long long w1 = *reinterpret_cast<const long long*>(bb0 + (size_t)c * 8192 + 4096);
            acc0 = __builtin_amdgcn_mfma_f32_16x16x32_fp8_fp8(a8, w0, acc0, 0, 0, 0);
            acc1 = __builtin_amdgcn_mfma_f32_16x16x32_fp8_fp8(a8, w1, acc1, 0, 0, 0);
        }

        // ---- epilogue: fast sigmoid/tanh via v_exp, reduce, atomic ----
        {
            const float S = 1.0f / 128.0f;
            float s[4];
            #pragma unroll
            for (int j = 0; j < 4; ++j) {
                const float xa = acc0[j] * S + bav;
                const float xb = acc1[j] * S + bbv;
                const float av = 1.0f / (1.0f + __expf(-xa));
                const float eb = __expf(2.0f * xb);
                const float bv = (eb - 1.0f) / (eb + 1.0f);
                s[j] = av * bv * wcv;
            }
            #pragma unroll
            for (int j = 0; j < 4; ++j) {
                s[j] += __shfl_xor(s[j], 1);
                s[j] += __shfl_xor(s[j], 2);
                s[j] += __shfl_xor(s[j], 4);
                s[j] += __shfl_xor(s[j], 8);
            }
            if (s15 == 0) {
                #pragma unroll
                for (int j = 0; j < 4; ++j)
                    atomicAdd(&score_raw[row0 + l4 * 4 + j], s[j]);
            }
        }

        t = tn;
        parity ^= 1;
    }
}

// ---- merged segment softmax: exp+sum, grid spin-barrier, divide ----
__global__ __launch_bounds__(256)
void seg_kernel(float* __restrict__ score_inout, const int* __restrict__ batch,
                float* __restrict__ denom, unsigned* __restrict__ counter, int n)
{
    __shared__ float sd[NSEG];
    const int t = threadIdx.x;
    if (t < NSEG) sd[t] = 0.0f;
    __syncthreads();

    const int stride = SGRID * 256;
    // phase 1: exp in place + per-block partial sums -> global denom
    for (int i = blockIdx.x * 256 + t; i < n; i += stride) {
        const float e = expf(score_inout[i]);
        score_inout[i] = e;
        atomicAdd(&sd[batch[i]], e);
    }
    __syncthreads();
    if (t < NSEG) atomicAdd(&denom[t], sd[t]);

    // grid barrier (all SGRID blocks are resident by construction)
    __threadfence();
    __syncthreads();
    if (t == 0) {
        atomicAdd(counter, 1u);
        while (atomicAdd(counter, 0u) < SGRID) { __builtin_amdgcn_s_sleep(8); }
    }
    __syncthreads();

    // cache final denoms via device-scope atomic reads
    if (t < NSEG) sd[t] = atomicAdd(&denom[t], 0.0f);
    __syncthreads();

    // phase 2: divide
    for (int i = blockIdx.x * 256 + t; i < n; i += stride)
        score_inout[i] = score_inout[i] / (sd[batch[i]] + 1e-16f);
}

// ---------------------------------------------------------------------------
extern "C" void kernel_launch(void* const* d_in, const int* in_sizes, int n_in,
                              void* d_out, int out_size, void* d_ws, size_t ws_size,
                              hipStream_t stream)
{
    const float* feat  = (const float*)d_in[0];
    const int*   batch = (const int*)d_in[1];
    // d_in[2] = istrain (unused; dropout is identity at eval)
    const float* Wa = (const float*)d_in[3];
    const float* ba = (const float*)d_in[4];
    const float* Wb = (const float*)d_in[5];
    const float* bb = (const float*)d_in[6];
    const float* Wc = (const float*)d_in[7];
    // d_in[8] = bc: uniform shift cancels in segment softmax -> dropped

    const int N = in_sizes[1];                 // 262144

    float* out_norm  = (float*)d_out;
    float* out_score = (float*)d_out + (size_t)N * DD;

    char* ws = (char*)d_ws;
    unsigned char* Wf8 = (unsigned char*)ws;                 // 256 KB
    float*    denom   = (float*)(ws + 2 * LL * DD);          // 64 f32
    unsigned* counter = (unsigned*)(ws + 2 * LL * DD + 256); // 1 u32

    prep_kernel<<<(2 * LL * DD + 255) / 256, 256, 0, stream>>>(Wa, Wb, Wf8, denom, counter, out_score);
    fused_main<<<GRID, 512, 0, stream>>>(feat, Wf8, ba, bb, Wc, out_norm, out_score);
    seg_kernel<<<SGRID, 256, 0, stream>>>(out_score, batch, denom, counter, N);
}